// Round 4
// baseline (362.301 us; speedup 1.0000x reference)
//
#include <hip/hip_runtime.h>
#include <hip/hip_bf16.h>
#include <cstddef>
#include <cstdint>

static constexpr int BSZ  = 8;
static constexpr int NN   = 512;
static constexpr int FF   = 512;
static constexpr int RR   = 16;
static constexpr int TWOF = 1024;

typedef __attribute__((ext_vector_type(8))) short short8;   // 8 bf16 in 4 VGPRs
typedef __attribute__((ext_vector_type(4))) float f32x4;

__device__ __forceinline__ ushort bf16_bits(float v) {
    union { __hip_bfloat16 h; ushort u; } cvt;
    cvt.h = __float2bfloat16(v);
    return cvt.u;
}

// ---------------------------------------------------------------------------
// Workspace layout (byte offsets, 256B aligned)
// ---------------------------------------------------------------------------
static constexpr size_t OFF_TB     = 0;         // f32 [8][512]
static constexpr size_t OFF_MB     = 16384;     // f32 [8][512]
static constexpr size_t OFF_MQ     = 32768;     // f32 [8][512]
static constexpr size_t OFF_MK     = 49152;     // f32 [8][512]
static constexpr size_t OFF_SQ     = 65536;     // f32 [8][512][16]
static constexpr size_t OFF_SK     = 327680;    // f32 [8][512][16]
static constexpr size_t OFF_WQET   = 589824;    // bf16 [8][16][1024]
static constexpr size_t OFF_WKET   = 851968;    // bf16 [8][16][1024]
static constexpr size_t OFF_XBF    = 5308416;   // bf16 [8][512][512]
static constexpr size_t OFF_XTBF   = 9502720;   // bf16 [8][512][512]  (x^T per b)
static constexpr size_t OFF_XORIBF = 13697024;  // bf16 [8][512][512]
static constexpr size_t OFF_NEWXBF = 17891328;  // bf16 [8][512][512]
static constexpr size_t OFF_WUT    = 22085632;  // bf16 [512][1024]    (Wu^T)

// ---------------------------------------------------------------------------
// Fused prep kernel (R0 form — no adj compress; adj handled inside attn):
//   blocks [0,1024):     x_ori -> xori_bf
//   blocks [1024,3072):  x -> x_bf + xT_bf (32x32 transpose tiles)
//   blocks [3072,3584):  Wu -> WuT_bf
//   blocks [3584,3712):  m-chain stage1: tb = elu(c @ Wfc)
// ---------------------------------------------------------------------------
__global__ __launch_bounds__(256) void k_prep(
    const float* __restrict__ x_ori, const float* __restrict__ x,
    const float* __restrict__ c, const float* __restrict__ Wfc,
    const float* __restrict__ Wu,
    ushort* __restrict__ xori_bf, ushort* __restrict__ x_bf,
    ushort* __restrict__ xT_bf, ushort* __restrict__ WuT,
    float* __restrict__ tb)
{
    int blk = blockIdx.x;
    int t = threadIdx.x;
    if (blk < 1024) {
        int idx = blk * 256 + t;
        float4 a = ((const float4*)x_ori)[idx * 2];
        float4 b = ((const float4*)x_ori)[idx * 2 + 1];
        uint4 s;
        s.x = (uint)bf16_bits(a.x) | ((uint)bf16_bits(a.y) << 16);
        s.y = (uint)bf16_bits(a.z) | ((uint)bf16_bits(a.w) << 16);
        s.z = (uint)bf16_bits(b.x) | ((uint)bf16_bits(b.y) << 16);
        s.w = (uint)bf16_bits(b.z) | ((uint)bf16_bits(b.w) << 16);
        ((uint4*)xori_bf)[idx] = s;
    } else if (blk < 3072) {
        __shared__ float tile[32][33];
        int bb = blk - 1024;
        int f0 = (bb & 15) * 32, i0 = ((bb >> 4) & 15) * 32, b = bb >> 8;
        int c2 = (t & 15) * 2, r = t >> 4;   // r in 0..15, c2 even in 0..30
#pragma unroll
        for (int rr = 0; rr < 32; rr += 16) {
            int i = i0 + r + rr;
            const float* xp = &x[((size_t)b * NN + i) * FF + f0 + c2];
            float v0 = xp[0], v1 = xp[1];
            tile[r + rr][c2] = v0;
            tile[r + rr][c2 + 1] = v1;
            *(uint*)&x_bf[((size_t)b * NN + i) * FF + f0 + c2] =
                (uint)bf16_bits(v0) | ((uint)bf16_bits(v1) << 16);
        }
        __syncthreads();
#pragma unroll
        for (int ff = 0; ff < 32; ff += 16) {
            int f = f0 + r + ff;
            *(uint*)&xT_bf[((size_t)b * FF + f) * NN + i0 + c2] =
                (uint)bf16_bits(tile[c2][r + ff]) |
                ((uint)bf16_bits(tile[c2 + 1][r + ff]) << 16);
        }
    } else if (blk < 3584) {
        __shared__ float tile2[32][33];
        int bb = blk - 3072;
        int f0 = (bb & 31) * 32, o0 = (bb >> 5) * 32;
        int cc = t & 31, r0 = t >> 5;
#pragma unroll
        for (int rr = 0; rr < 32; rr += 8)
            tile2[r0 + rr][cc] = Wu[(size_t)(f0 + r0 + rr) * FF + o0 + cc];
        __syncthreads();
#pragma unroll
        for (int rr = 0; rr < 32; rr += 8)
            WuT[(size_t)(o0 + r0 + rr) * TWOF + f0 + cc] = bf16_bits(tile2[cc][r0 + rr]);
    } else {
        // m-chain stage 1: tb = elu(c @ Wfc), grid-equivalent (16,8)
        __shared__ float red1[8][32];
        int bb = blk - 3584;
        int b = bb >> 4, f0 = (bb & 15) * 32;
        int f = t & 31, kq = t >> 5;
        const float* vb = c + (size_t)b * FF;
        float acc = 0.f;
        int ks = kq * 64;
#pragma unroll 8
        for (int k = ks; k < ks + 64; ++k)
            acc = fmaf(vb[k], Wfc[(size_t)k * FF + f0 + f], acc);
        red1[kq][f] = acc;
        __syncthreads();
        if (kq == 0) {
            acc += red1[1][f] + red1[2][f] + red1[3][f] + red1[4][f] +
                   red1[5][f] + red1[6][f] + red1[7][f];
            tb[(size_t)b * FF + f0 + f] = (acc > 0.f) ? acc : expm1f(acc);
        }
    }
}

// ---------------------------------------------------------------------------
// Batched GEMV: vout[b,f] = vin[b,:] @ W[:,f]
// grid (16 fb, 8 b), block 256 = (32 f, 8 kq)
// ---------------------------------------------------------------------------
__global__ __launch_bounds__(256) void k_matvec(const float* __restrict__ vin,
                                                const float* __restrict__ W,
                                                float* __restrict__ vout) {
    __shared__ float red[8][32];
    int b = blockIdx.y;
    int f0 = blockIdx.x * 32;
    int t = threadIdx.x;
    int f = t & 31, kq = t >> 5;
    const float* vb = vin + (size_t)b * FF;
    float acc = 0.f;
    int ks = kq * 64;
#pragma unroll 8
    for (int k = ks; k < ks + 64; ++k)
        acc = fmaf(vb[k], W[(size_t)k * FF + f0 + f], acc);
    red[kq][f] = acc;
    __syncthreads();
    if (kq == 0) {
        acc += red[1][f] + red[2][f] + red[3][f] + red[4][f] +
               red[5][f] + red[6][f] + red[7][f];
        vout[(size_t)b * FF + f0 + f] = acc;
    }
}

// mq = m @ Wqc ; mk = m @ Wkc
__global__ __launch_bounds__(256) void k_mqk(const float* __restrict__ m,
                                             const float* __restrict__ Wqc,
                                             const float* __restrict__ Wkc,
                                             float* __restrict__ mq,
                                             float* __restrict__ mk) {
    __shared__ float redq[8][32];
    __shared__ float redk[8][32];
    int b = blockIdx.y;
    int f0 = blockIdx.x * 32;
    int t = threadIdx.x;
    int f = t & 31, kq = t >> 5;
    const float* mb = m + (size_t)b * FF;
    float aq = 0.f, ak = 0.f;
    int ks = kq * 64;
#pragma unroll 8
    for (int k = ks; k < ks + 64; ++k) {
        float mv = mb[k];
        aq = fmaf(mv, Wqc[(size_t)k * FF + f0 + f], aq);
        ak = fmaf(mv, Wkc[(size_t)k * FF + f0 + f], ak);
    }
    redq[kq][f] = aq;
    redk[kq][f] = ak;
    __syncthreads();
    if (kq == 0) {
        aq += redq[1][f] + redq[2][f] + redq[3][f] + redq[4][f] +
              redq[5][f] + redq[6][f] + redq[7][f];
        ak += redk[1][f] + redk[2][f] + redk[3][f] + redk[4][f] +
              redk[5][f] + redk[6][f] + redk[7][f];
        mq[(size_t)b * FF + f0 + f] = aq;
        mk[(size_t)b * FF + f0 + f] = ak;
    }
}

// ---------------------------------------------------------------------------
// W_eff^T[b,r,k] = sum_f W[k,f] * mvec[b,f] * Wa[waRowOff+f, r]  (bf16 out)
// grid (16 kchunks, 8 b, 2 {q,k}), block 256.  f-loop vectorized x4.
// ---------------------------------------------------------------------------
__global__ __launch_bounds__(256) void k_weff(const float* __restrict__ Wqv,
                                              const float* __restrict__ Wkv,
                                              const float* __restrict__ Wa,
                                              const float* __restrict__ mqv,
                                              const float* __restrict__ mkv,
                                              ushort* __restrict__ WqEt,
                                              ushort* __restrict__ WkEt) {
    int z = blockIdx.z;
    const float* W = z ? Wkv : Wqv;
    const float* mvec = z ? mkv : mqv;
    ushort* WeffT = z ? WkEt : WqEt;
    int waRowOff = z ? FF : 0;

    __shared__ float4 wa4[FF * 4];  // [f][r4] scaled Wa, 32 KiB
    int tid = threadIdx.x;
    int b = blockIdx.y;
    const float* mv = mvec + (size_t)b * FF;
#pragma unroll
    for (int qq = 0; qq < 8; ++qq) {
        int idx = tid + qq * 256;
        int f = idx >> 2, rq = idx & 3;
        float4 w = *reinterpret_cast<const float4*>(Wa + (size_t)(waRowOff + f) * RR + rq * 4);
        float s = mv[f];
        float4 o;
        o.x = w.x * s; o.y = w.y * s; o.z = w.z * s; o.w = w.w * s;
        wa4[idx] = o;
    }
    __syncthreads();
    int k_l = tid >> 2, r4 = tid & 3;
    int k = blockIdx.x * 64 + k_l;
    const float4* Wrow4 = reinterpret_cast<const float4*>(W + (size_t)k * FF);
    float4 acc = {0.f, 0.f, 0.f, 0.f};
#pragma unroll 4
    for (int f4 = 0; f4 < FF / 4; ++f4) {
        float4 w = Wrow4[f4];
        float4 v0 = wa4[(f4 * 4 + 0) * 4 + r4];
        float4 v1 = wa4[(f4 * 4 + 1) * 4 + r4];
        float4 v2 = wa4[(f4 * 4 + 2) * 4 + r4];
        float4 v3 = wa4[(f4 * 4 + 3) * 4 + r4];
        acc.x = fmaf(w.x, v0.x, acc.x); acc.y = fmaf(w.x, v0.y, acc.y);
        acc.z = fmaf(w.x, v0.z, acc.z); acc.w = fmaf(w.x, v0.w, acc.w);
        acc.x = fmaf(w.y, v1.x, acc.x); acc.y = fmaf(w.y, v1.y, acc.y);
        acc.z = fmaf(w.y, v1.z, acc.z); acc.w = fmaf(w.y, v1.w, acc.w);
        acc.x = fmaf(w.z, v2.x, acc.x); acc.y = fmaf(w.z, v2.y, acc.y);
        acc.z = fmaf(w.z, v2.z, acc.z); acc.w = fmaf(w.z, v2.w, acc.w);
        acc.x = fmaf(w.w, v3.x, acc.x); acc.y = fmaf(w.w, v3.y, acc.y);
        acc.z = fmaf(w.w, v3.z, acc.z); acc.w = fmaf(w.w, v3.w, acc.w);
    }
    WeffT[((size_t)b * RR + r4 * 4 + 0) * TWOF + k] = bf16_bits(acc.x);
    WeffT[((size_t)b * RR + r4 * 4 + 1) * TWOF + k] = bf16_bits(acc.y);
    WeffT[((size_t)b * RR + r4 * 4 + 2) * TWOF + k] = bf16_bits(acc.z);
    WeffT[((size_t)b * RR + r4 * 4 + 3) * TWOF + k] = bf16_bits(acc.w);
}

// ---------------------------------------------------------------------------
// sq/sk via MFMA, LDS-free. grid (16 m-tiles of 32, 8 b), block 256 = 4 waves
// ---------------------------------------------------------------------------
__global__ __launch_bounds__(256) void k_sqsk(const ushort* __restrict__ x_bf,
                                              const ushort* __restrict__ xori_bf,
                                              const ushort* __restrict__ WqEt,
                                              const ushort* __restrict__ WkEt,
                                              float* __restrict__ sq,
                                              float* __restrict__ sk) {
    int t = threadIdx.x;
    int b = blockIdx.y;
    int m0 = blockIdx.x * 32;
    int lane = t & 63, w = t >> 6;
    int sub = w & 1, isK = w >> 1;
    int m_l = lane & 15, q = lane >> 4;
    int row = m0 + sub * 16 + m_l;
    const ushort* Bt = (isK ? WkEt : WqEt) + ((size_t)b * RR + m_l) * TWOF;
    f32x4 acc = {0.f, 0.f, 0.f, 0.f};
#pragma unroll
    for (int k0 = 0; k0 < TWOF; k0 += 32) {
        const ushort* src = (k0 < FF) ? x_bf : xori_bf;
        int kc = k0 & (FF - 1);
        short8 af = *(const short8*)(src + ((size_t)b * NN + row) * FF + kc + q * 8);
        short8 bf = *(const short8*)(Bt + k0 + q * 8);
        acc = __builtin_amdgcn_mfma_f32_16x16x32_bf16(af, bf, acc, 0, 0, 0);
    }
    float* dst = isK ? sk : sq;
#pragma unroll
    for (int r = 0; r < 4; ++r) {
        int i = m0 + sub * 16 + q * 4 + r;
        dst[((size_t)b * NN + i) * RR + m_l] = acc[r];
    }
}

// ---------------------------------------------------------------------------
// Fused adj-compress + scores + softmax + PV: newx[b, m0..m0+16, :].
// grid (32 i-tiles of 16, 8 b) = 256 blocks, 1 block/CU.
//   Phase 0: this block's adj slice is CONTIGUOUS 512 KB. Stream it with
//            coalesced int4 loads (1 KB/wave/instr, unroll-8 => 32 KB in
//            flight per CU, well above the ~9 KB latency-BW product) and
//            quad-shfl pack 16 relation bits -> u16 masks in LDS (16 KB).
//            This IS the kernel's HBM roofline term (~21 us chip-wide).
//   Phase A+B fused: scores for row r held in 32 registers (1 LDS ushort +
//            4 L1/L2-hot float4 of sk per j); softmax via in-register max
//            + shfl reductions across the 16-lane row group; P=bf16(exp).
//   Phase C: newx = P(16x512) @ x via MFMA; B-frags 16-B loads from
//            L2/L3-hot xT_bf; epilogue scales by 1/rowsum.
// LDS: ~33 KB. All 16 P rows are real work (no zero-padding waste).
// ---------------------------------------------------------------------------
__global__ __launch_bounds__(256, 2) void k_attn_pv(const int* __restrict__ adj,
                                                    const float* __restrict__ sq,
                                                    const float* __restrict__ sk,
                                                    const ushort* __restrict__ xT_bf,
                                                    ushort* __restrict__ newx_bf) {
    constexpr int ZS = 520;              // padded row stride (ushorts)
    __shared__ ushort P[16 * ZS];        // 16.6 KB
    __shared__ ushort mask_lds[16 * NN]; // 16 KB
    __shared__ float  rowsum[16];
    int t = threadIdx.x;
    int b = blockIdx.y;
    int m0 = blockIdx.x * 16;

    // ---- Phase 0: stream adj slice -> u16 masks in LDS ----
    {
        const int4* a4 = (const int4*)adj + ((size_t)b * NN + m0) * (NN * RR / 4);
        uint* ml = (uint*)mask_lds;
#pragma unroll 8
        for (int it = 0; it < 128; ++it) {
            int4 v = a4[it * 256 + t];
            uint bits = (uint)v.x | ((uint)v.y << 1) | ((uint)v.z << 2) | ((uint)v.w << 3);
            uint mp = bits << ((t & 3) * 4);
            mp |= (uint)__shfl_xor((int)mp, 1, 64);
            mp |= (uint)__shfl_xor((int)mp, 2, 64);
            uint hi = (uint)__shfl_xor((int)mp, 4, 64);
            if ((t & 7) == 0) {
                int p = (it * 256 + t) >> 2;   // pair index = r*512 + j (even)
                ml[p >> 1] = (mp & 0xFFFFu) | (hi << 16);
            }
        }
    }
    __syncthreads();

    // ---- Phase A+B fused: scores in registers -> softmax -> P ----
    {
        int r = t >> 4, cc = t & 15;    // r 0..15, cc 0..15
        int i = m0 + r;
        const float4* sqp = (const float4*)(sq + ((size_t)b * NN + i) * RR);
        float4 q0 = sqp[0], q1 = sqp[1], q2 = sqp[2], q3 = sqp[3];
        float sv[16] = {q0.x, q0.y, q0.z, q0.w, q1.x, q1.y, q1.z, q1.w,
                        q2.x, q2.y, q2.z, q2.w, q3.x, q3.y, q3.z, q3.w};
        float z[32];
#pragma unroll 4
        for (int it = 0; it < 32; ++it) {
            int j = it * 16 + cc;
            uint mk = mask_lds[r * NN + j];
            const float4* kp = (const float4*)(sk + ((size_t)b * NN + j) * RR);
            float4 s0 = kp[0], s1 = kp[1], s2 = kp[2], s3 = kp[3];
            float ks[16] = {s0.x, s0.y, s0.z, s0.w, s1.x, s1.y, s1.z, s1.w,
                            s2.x, s2.y, s2.z, s2.w, s3.x, s3.y, s3.z, s3.w};
            float ssum = 0.f;
#pragma unroll
            for (int ridx = 0; ridx < 16; ++ridx) {
                float v_ = sv[ridx] + ks[ridx];
                v_ = fmaxf(v_, 0.2f * v_);
                ssum = fmaf(v_, (float)((mk >> ridx) & 1u), ssum);
            }
            z[it] = mk ? ssum : -9e15f;
        }
        float mx = z[0];
#pragma unroll
        for (int it = 1; it < 32; ++it) mx = fmaxf(mx, z[it]);
#pragma unroll
        for (int off = 1; off < 16; off <<= 1) mx = fmaxf(mx, __shfl_xor(mx, off, 64));
        float sum = 0.f;
        ushort* pr = &P[r * ZS];
#pragma unroll
        for (int it = 0; it < 32; ++it) {
            float e = __expf(z[it] - mx);
            pr[it * 16 + cc] = bf16_bits(e);
            sum += e;
        }
#pragma unroll
        for (int off = 1; off < 16; off <<= 1) sum += __shfl_xor(sum, off, 64);
        if (cc == 0) rowsum[r] = sum;
    }
    __syncthreads();

    // ---- Phase C: newx tile = P(16x512) @ x(512x512) via MFMA ----
    {
        int w = t >> 6, lane = t & 63;
        int m_l = lane & 15, q = lane >> 4;
        int n0w = w * 128;
        f32x4 acc[8] = {};
        const ushort* xTb = xT_bf + (size_t)b * FF * NN;
        for (int k0 = 0; k0 < NN; k0 += 32) {
            short8 af = *(const short8*)(&P[m_l * ZS + k0 + q * 8]);
#pragma unroll
            for (int nb = 0; nb < 8; ++nb) {
                int n = n0w + nb * 16 + m_l;
                short8 bfr = *(const short8*)(xTb + (size_t)n * NN + k0 + q * 8);
                acc[nb] = __builtin_amdgcn_mfma_f32_16x16x32_bf16(af, bfr, acc[nb], 0, 0, 0);
            }
        }
        float inv[4];
#pragma unroll
        for (int rg = 0; rg < 4; ++rg) inv[rg] = 1.f / rowsum[q * 4 + rg];
#pragma unroll
        for (int nb = 0; nb < 8; ++nb) {
#pragma unroll
            for (int rg = 0; rg < 4; ++rg) {
                int i = m0 + q * 4 + rg;
                int f = n0w + nb * 16 + m_l;
                newx_bf[((size_t)b * NN + i) * FF + f] = bf16_bits(acc[nb][rg] * inv[rg]);
            }
        }
    }
}

// ---------------------------------------------------------------------------
// bf16 MFMA GEMM: C[b] (MxN) = A[b] (MxK row-major, split at k=512) @ BT^T
// 64x64 tile; two BK=32 stages per barrier-pair. grid (N/64, M/64, 8)
// ---------------------------------------------------------------------------
__global__ __launch_bounds__(256) void k_gemm(const ushort* __restrict__ A1, size_t sA1,
                                              const ushort* __restrict__ A2, size_t sA2,
                                              const ushort* __restrict__ BT, size_t sBT,
                                              float* __restrict__ Cf, size_t sC,
                                              int K, int ldBT) {
    __shared__ ushort As[2][64 * 40];  // stride 40 ushort = 80 B (16B-aligned rows)
    __shared__ ushort Bs[2][64 * 40];
    int t = threadIdx.x;
    int n0 = blockIdx.x * 64, m0 = blockIdx.y * 64, b = blockIdx.z;
    int row = t >> 2, c8 = (t & 3) * 8;
    int lane = t & 63, w = t >> 6;
    int m_l = lane & 15, q = lane >> 4;
    f32x4 acc[4] = {{0.f,0.f,0.f,0.f},{0.f,0.f,0.f,0.f},{0.f,0.f,0.f,0.f},{0.f,0.f,0.f,0.f}};
    const ushort* BTb = BT + (size_t)b * sBT;
    for (int k0 = 0; k0 < K; k0 += 64) {
#pragma unroll
        for (int h = 0; h < 2; ++h) {
            int kk = k0 + h * 32;
            const ushort* Aab; int kc;
            if (kk < FF) { Aab = A1 + (size_t)b * sA1; kc = kk; }
            else         { Aab = A2 + (size_t)b * sA2; kc = kk - FF; }
            uint4 av = *(const uint4*)(Aab + (size_t)(m0 + row) * FF + kc + c8);
            uint4 bv = *(const uint4*)(BTb + (size_t)(n0 + row) * ldBT + kk + c8);
            *(uint4*)(&As[h][row * 40 + c8]) = av;
            *(uint4*)(&Bs[h][row * 40 + c8]) = bv;
        }
        __syncthreads();
#pragma unroll
        for (int h = 0; h < 2; ++h) {
            short8 af = *(const short8*)(&As[h][(w * 16 + m_l) * 40 + q * 8]);
#pragma unroll
            for (int nb = 0; nb < 4; ++nb) {
                short8 bfr = *(const short8*)(&Bs[h][(nb * 16 + m_l) * 40 + q * 8]);
                acc[nb] = __builtin_amdgcn_mfma_f32_16x16x32_bf16(af, bfr, acc[nb], 0, 0, 0);
            }
        }
        __syncthreads();
    }
#pragma unroll
    for (int nb = 0; nb < 4; ++nb) {
#pragma unroll
        for (int r = 0; r < 4; ++r) {
            int mi = m0 + w * 16 + q * 4 + r;
            int ni = n0 + nb * 16 + m_l;
            Cf[(size_t)b * sC + (size_t)mi * FF + ni] = acc[nb][r];
        }
    }
}

// ---------------------------------------------------------------------------
// Launch
// ---------------------------------------------------------------------------
extern "C" void kernel_launch(void* const* d_in, const int* in_sizes, int n_in,
                              void* d_out, int out_size, void* d_ws, size_t ws_size,
                              hipStream_t stream) {
    const float* x_ori = (const float*)d_in[0];
    const float* x     = (const float*)d_in[1];
    const float* c     = (const float*)d_in[2];
    const int*   adj   = (const int*)d_in[3];
    const float* Wfc   = (const float*)d_in[4];
    const float* Wdc   = (const float*)d_in[5];
    const float* Wqv   = (const float*)d_in[6];
    const float* Wkv   = (const float*)d_in[7];
    const float* Wqc   = (const float*)d_in[8];
    const float* Wkc   = (const float*)d_in[9];
    const float* Wa    = (const float*)d_in[10];
    const float* Wu    = (const float*)d_in[11];
    float* out = (float*)d_out;

    char* ws = (char*)d_ws;
    float*  tb      = (float*)(ws + OFF_TB);
    float*  mb      = (float*)(ws + OFF_MB);
    float*  mq      = (float*)(ws + OFF_MQ);
    float*  mk      = (float*)(ws + OFF_MK);
    float*  sq      = (float*)(ws + OFF_SQ);
    float*  sk      = (float*)(ws + OFF_SK);
    ushort* WqEt    = (ushort*)(ws + OFF_WQET);
    ushort* WkEt    = (ushort*)(ws + OFF_WKET);
    ushort* x_bf    = (ushort*)(ws + OFF_XBF);
    ushort* xT_bf   = (ushort*)(ws + OFF_XTBF);
    ushort* xori_bf = (ushort*)(ws + OFF_XORIBF);
    ushort* newx_bf = (ushort*)(ws + OFF_NEWXBF);
    ushort* WuT     = (ushort*)(ws + OFF_WUT);

    dim3 blk(256);

    // 1) conversions/transposes + m-chain stage 1
    k_prep<<<dim3(3712), blk, 0, stream>>>(x_ori, x, c, Wfc, Wu,
                                           xori_bf, x_bf, xT_bf, WuT, tb);

    // 2) m-chain stages 2-3
    k_matvec<<<dim3(16, BSZ), blk, 0, stream>>>(tb, Wdc, mb);
    k_mqk<<<dim3(16, BSZ), blk, 0, stream>>>(mb, Wqc, Wkc, mq, mk);

    // 3) effective low-rank weights (q and k via blockIdx.z)
    k_weff<<<dim3(16, BSZ, 2), blk, 0, stream>>>(Wqv, Wkv, Wa, mq, mk, WqEt, WkEt);

    // 4) sq / sk via LDS-free MFMA
    k_sqsk<<<dim3(16, BSZ), blk, 0, stream>>>(x_bf, xori_bf, WqEt, WkEt, sq, sk);

    // 5) fused adj-compress + scores + softmax + PV -> newx (bf16)
    k_attn_pv<<<dim3(32, BSZ), blk, 0, stream>>>(adj, sq, sk, xT_bf, newx_bf);

    // 6) out = [x | new_x] @ Wu
    k_gemm<<<dim3(8, 8, BSZ), blk, 0, stream>>>(
        x_bf, (size_t)NN * FF, newx_bf, (size_t)NN * FF,
        WuT, (size_t)0, out, (size_t)NN * FF, TWOF, TWOF);
}

// Round 5
// 308.685 us; speedup vs baseline: 1.1737x; 1.1737x over previous
//
#include <hip/hip_runtime.h>
#include <hip/hip_bf16.h>
#include <cstddef>
#include <cstdint>

static constexpr int BSZ  = 8;
static constexpr int NN   = 512;
static constexpr int FF   = 512;
static constexpr int RR   = 16;
static constexpr int TWOF = 1024;

typedef __attribute__((ext_vector_type(8))) short short8;   // 8 bf16 in 4 VGPRs
typedef __attribute__((ext_vector_type(4))) float f32x4;

__device__ __forceinline__ ushort bf16_bits(float v) {
    union { __hip_bfloat16 h; ushort u; } cvt;
    cvt.h = __float2bfloat16(v);
    return cvt.u;
}

// ---------------------------------------------------------------------------
// Workspace layout (byte offsets, 256B aligned)
// ---------------------------------------------------------------------------
static constexpr size_t OFF_TB     = 0;         // f32 [8][512]
static constexpr size_t OFF_MB     = 16384;     // f32 [8][512]
static constexpr size_t OFF_MQ     = 32768;     // f32 [8][512]
static constexpr size_t OFF_MK     = 49152;     // f32 [8][512]
static constexpr size_t OFF_SQ     = 65536;     // f32 [8][512][16]
static constexpr size_t OFF_SK     = 327680;    // f32 [8][512][16]
static constexpr size_t OFF_WQET   = 589824;    // bf16 [8][16][1024]
static constexpr size_t OFF_WKET   = 851968;    // bf16 [8][16][1024]
static constexpr size_t OFF_XBF    = 5308416;   // bf16 [8][512][512]
static constexpr size_t OFF_XTBF   = 9502720;   // bf16 [8][512][512]  (x^T per b)
static constexpr size_t OFF_XORIBF = 13697024;  // bf16 [8][512][512]
static constexpr size_t OFF_NEWXBF = 17891328;  // bf16 [8][512][512]
static constexpr size_t OFF_WUT    = 22085632;  // bf16 [512][1024]    (Wu^T)
static constexpr size_t OFF_Z      = 23134208;  // f32  [8][512][512]  (scores)

// ---------------------------------------------------------------------------
// Fused prep kernel (R0 form):
//   blocks [0,1024):     x_ori -> xori_bf
//   blocks [1024,3072):  x -> x_bf + xT_bf (32x32 transpose tiles)
//   blocks [3072,3584):  Wu -> WuT_bf
//   blocks [3584,3712):  m-chain stage1: tb = elu(c @ Wfc)
// ---------------------------------------------------------------------------
__global__ __launch_bounds__(256) void k_prep(
    const float* __restrict__ x_ori, const float* __restrict__ x,
    const float* __restrict__ c, const float* __restrict__ Wfc,
    const float* __restrict__ Wu,
    ushort* __restrict__ xori_bf, ushort* __restrict__ x_bf,
    ushort* __restrict__ xT_bf, ushort* __restrict__ WuT,
    float* __restrict__ tb)
{
    int blk = blockIdx.x;
    int t = threadIdx.x;
    if (blk < 1024) {
        int idx = blk * 256 + t;
        float4 a = ((const float4*)x_ori)[idx * 2];
        float4 b = ((const float4*)x_ori)[idx * 2 + 1];
        uint4 s;
        s.x = (uint)bf16_bits(a.x) | ((uint)bf16_bits(a.y) << 16);
        s.y = (uint)bf16_bits(a.z) | ((uint)bf16_bits(a.w) << 16);
        s.z = (uint)bf16_bits(b.x) | ((uint)bf16_bits(b.y) << 16);
        s.w = (uint)bf16_bits(b.z) | ((uint)bf16_bits(b.w) << 16);
        ((uint4*)xori_bf)[idx] = s;
    } else if (blk < 3072) {
        __shared__ float tile[32][33];
        int bb = blk - 1024;
        int f0 = (bb & 15) * 32, i0 = ((bb >> 4) & 15) * 32, b = bb >> 8;
        int c2 = (t & 15) * 2, r = t >> 4;   // r in 0..15, c2 even in 0..30
#pragma unroll
        for (int rr = 0; rr < 32; rr += 16) {
            int i = i0 + r + rr;
            const float* xp = &x[((size_t)b * NN + i) * FF + f0 + c2];
            float v0 = xp[0], v1 = xp[1];
            tile[r + rr][c2] = v0;
            tile[r + rr][c2 + 1] = v1;
            *(uint*)&x_bf[((size_t)b * NN + i) * FF + f0 + c2] =
                (uint)bf16_bits(v0) | ((uint)bf16_bits(v1) << 16);
        }
        __syncthreads();
#pragma unroll
        for (int ff = 0; ff < 32; ff += 16) {
            int f = f0 + r + ff;
            *(uint*)&xT_bf[((size_t)b * FF + f) * NN + i0 + c2] =
                (uint)bf16_bits(tile[c2][r + ff]) |
                ((uint)bf16_bits(tile[c2 + 1][r + ff]) << 16);
        }
    } else if (blk < 3584) {
        __shared__ float tile2[32][33];
        int bb = blk - 3072;
        int f0 = (bb & 31) * 32, o0 = (bb >> 5) * 32;
        int cc = t & 31, r0 = t >> 5;
#pragma unroll
        for (int rr = 0; rr < 32; rr += 8)
            tile2[r0 + rr][cc] = Wu[(size_t)(f0 + r0 + rr) * FF + o0 + cc];
        __syncthreads();
#pragma unroll
        for (int rr = 0; rr < 32; rr += 8)
            WuT[(size_t)(o0 + r0 + rr) * TWOF + f0 + cc] = bf16_bits(tile2[cc][r0 + rr]);
    } else {
        // m-chain stage 1: tb = elu(c @ Wfc), grid-equivalent (16,8)
        __shared__ float red1[8][32];
        int bb = blk - 3584;
        int b = bb >> 4, f0 = (bb & 15) * 32;
        int f = t & 31, kq = t >> 5;
        const float* vb = c + (size_t)b * FF;
        float acc = 0.f;
        int ks = kq * 64;
#pragma unroll 8
        for (int k = ks; k < ks + 64; ++k)
            acc = fmaf(vb[k], Wfc[(size_t)k * FF + f0 + f], acc);
        red1[kq][f] = acc;
        __syncthreads();
        if (kq == 0) {
            acc += red1[1][f] + red1[2][f] + red1[3][f] + red1[4][f] +
                   red1[5][f] + red1[6][f] + red1[7][f];
            tb[(size_t)b * FF + f0 + f] = (acc > 0.f) ? acc : expm1f(acc);
        }
    }
}

// ---------------------------------------------------------------------------
// Batched GEMV: vout[b,f] = vin[b,:] @ W[:,f]
// grid (16 fb, 8 b), block 256 = (32 f, 8 kq)
// ---------------------------------------------------------------------------
__global__ __launch_bounds__(256) void k_matvec(const float* __restrict__ vin,
                                                const float* __restrict__ W,
                                                float* __restrict__ vout) {
    __shared__ float red[8][32];
    int b = blockIdx.y;
    int f0 = blockIdx.x * 32;
    int t = threadIdx.x;
    int f = t & 31, kq = t >> 5;
    const float* vb = vin + (size_t)b * FF;
    float acc = 0.f;
    int ks = kq * 64;
#pragma unroll 8
    for (int k = ks; k < ks + 64; ++k)
        acc = fmaf(vb[k], W[(size_t)k * FF + f0 + f], acc);
    red[kq][f] = acc;
    __syncthreads();
    if (kq == 0) {
        acc += red[1][f] + red[2][f] + red[3][f] + red[4][f] +
               red[5][f] + red[6][f] + red[7][f];
        vout[(size_t)b * FF + f0 + f] = acc;
    }
}

// mq = m @ Wqc ; mk = m @ Wkc
__global__ __launch_bounds__(256) void k_mqk(const float* __restrict__ m,
                                             const float* __restrict__ Wqc,
                                             const float* __restrict__ Wkc,
                                             float* __restrict__ mq,
                                             float* __restrict__ mk) {
    __shared__ float redq[8][32];
    __shared__ float redk[8][32];
    int b = blockIdx.y;
    int f0 = blockIdx.x * 32;
    int t = threadIdx.x;
    int f = t & 31, kq = t >> 5;
    const float* mb = m + (size_t)b * FF;
    float aq = 0.f, ak = 0.f;
    int ks = kq * 64;
#pragma unroll 8
    for (int k = ks; k < ks + 64; ++k) {
        float mv = mb[k];
        aq = fmaf(mv, Wqc[(size_t)k * FF + f0 + f], aq);
        ak = fmaf(mv, Wkc[(size_t)k * FF + f0 + f], ak);
    }
    redq[kq][f] = aq;
    redk[kq][f] = ak;
    __syncthreads();
    if (kq == 0) {
        aq += redq[1][f] + redq[2][f] + redq[3][f] + redq[4][f] +
              redq[5][f] + redq[6][f] + redq[7][f];
        ak += redk[1][f] + redk[2][f] + redk[3][f] + redk[4][f] +
              redk[5][f] + redk[6][f] + redk[7][f];
        mq[(size_t)b * FF + f0 + f] = aq;
        mk[(size_t)b * FF + f0 + f] = ak;
    }
}

// ---------------------------------------------------------------------------
// W_eff^T[b,r,k] = sum_f W[k,f] * mvec[b,f] * Wa[waRowOff+f, r]  (bf16 out)
// grid (16 kchunks, 8 b, 2 {q,k}), block 256.  f-loop vectorized x4.
// ---------------------------------------------------------------------------
__global__ __launch_bounds__(256) void k_weff(const float* __restrict__ Wqv,
                                              const float* __restrict__ Wkv,
                                              const float* __restrict__ Wa,
                                              const float* __restrict__ mqv,
                                              const float* __restrict__ mkv,
                                              ushort* __restrict__ WqEt,
                                              ushort* __restrict__ WkEt) {
    int z = blockIdx.z;
    const float* W = z ? Wkv : Wqv;
    const float* mvec = z ? mkv : mqv;
    ushort* WeffT = z ? WkEt : WqEt;
    int waRowOff = z ? FF : 0;

    __shared__ float4 wa4[FF * 4];  // [f][r4] scaled Wa, 32 KiB
    int tid = threadIdx.x;
    int b = blockIdx.y;
    const float* mv = mvec + (size_t)b * FF;
#pragma unroll
    for (int qq = 0; qq < 8; ++qq) {
        int idx = tid + qq * 256;
        int f = idx >> 2, rq = idx & 3;
        float4 w = *reinterpret_cast<const float4*>(Wa + (size_t)(waRowOff + f) * RR + rq * 4);
        float s = mv[f];
        float4 o;
        o.x = w.x * s; o.y = w.y * s; o.z = w.z * s; o.w = w.w * s;
        wa4[idx] = o;
    }
    __syncthreads();
    int k_l = tid >> 2, r4 = tid & 3;
    int k = blockIdx.x * 64 + k_l;
    const float4* Wrow4 = reinterpret_cast<const float4*>(W + (size_t)k * FF);
    float4 acc = {0.f, 0.f, 0.f, 0.f};
#pragma unroll 4
    for (int f4 = 0; f4 < FF / 4; ++f4) {
        float4 w = Wrow4[f4];
        float4 v0 = wa4[(f4 * 4 + 0) * 4 + r4];
        float4 v1 = wa4[(f4 * 4 + 1) * 4 + r4];
        float4 v2 = wa4[(f4 * 4 + 2) * 4 + r4];
        float4 v3 = wa4[(f4 * 4 + 3) * 4 + r4];
        acc.x = fmaf(w.x, v0.x, acc.x); acc.y = fmaf(w.x, v0.y, acc.y);
        acc.z = fmaf(w.x, v0.z, acc.z); acc.w = fmaf(w.x, v0.w, acc.w);
        acc.x = fmaf(w.y, v1.x, acc.x); acc.y = fmaf(w.y, v1.y, acc.y);
        acc.z = fmaf(w.y, v1.z, acc.z); acc.w = fmaf(w.y, v1.w, acc.w);
        acc.x = fmaf(w.z, v2.x, acc.x); acc.y = fmaf(w.z, v2.y, acc.y);
        acc.z = fmaf(w.z, v2.z, acc.z); acc.w = fmaf(w.z, v2.w, acc.w);
        acc.x = fmaf(w.w, v3.x, acc.x); acc.y = fmaf(w.w, v3.y, acc.y);
        acc.z = fmaf(w.w, v3.z, acc.z); acc.w = fmaf(w.w, v3.w, acc.w);
    }
    WeffT[((size_t)b * RR + r4 * 4 + 0) * TWOF + k] = bf16_bits(acc.x);
    WeffT[((size_t)b * RR + r4 * 4 + 1) * TWOF + k] = bf16_bits(acc.y);
    WeffT[((size_t)b * RR + r4 * 4 + 2) * TWOF + k] = bf16_bits(acc.z);
    WeffT[((size_t)b * RR + r4 * 4 + 3) * TWOF + k] = bf16_bits(acc.w);
}

// ---------------------------------------------------------------------------
// sq/sk via MFMA, LDS-free. grid (16 m-tiles of 32, 8 b), block 256 = 4 waves
// ---------------------------------------------------------------------------
__global__ __launch_bounds__(256) void k_sqsk(const ushort* __restrict__ x_bf,
                                              const ushort* __restrict__ xori_bf,
                                              const ushort* __restrict__ WqEt,
                                              const ushort* __restrict__ WkEt,
                                              float* __restrict__ sq,
                                              float* __restrict__ sk) {
    int t = threadIdx.x;
    int b = blockIdx.y;
    int m0 = blockIdx.x * 32;
    int lane = t & 63, w = t >> 6;
    int sub = w & 1, isK = w >> 1;
    int m_l = lane & 15, q = lane >> 4;
    int row = m0 + sub * 16 + m_l;
    const ushort* Bt = (isK ? WkEt : WqEt) + ((size_t)b * RR + m_l) * TWOF;
    f32x4 acc = {0.f, 0.f, 0.f, 0.f};
#pragma unroll
    for (int k0 = 0; k0 < TWOF; k0 += 32) {
        const ushort* src = (k0 < FF) ? x_bf : xori_bf;
        int kc = k0 & (FF - 1);
        short8 af = *(const short8*)(src + ((size_t)b * NN + row) * FF + kc + q * 8);
        short8 bf = *(const short8*)(Bt + k0 + q * 8);
        acc = __builtin_amdgcn_mfma_f32_16x16x32_bf16(af, bf, acc, 0, 0, 0);
    }
    float* dst = isK ? sk : sq;
#pragma unroll
    for (int r = 0; r < 4; ++r) {
        int i = m0 + sub * 16 + q * 4 + r;
        dst[((size_t)b * NN + i) * RR + m_l] = acc[r];
    }
}

// ---------------------------------------------------------------------------
// Masked scores as a pure streaming kernel (the adj roofline term).
// z[b,i,j] = sum_r leakyrelu(sq[b,i,r]+sk[b,j,r]) * adj[b,i,j,r], or -9e15.
// grid (4 j-tiles of 128, 128 i-tiles of 4, 8 b) = 4096 blocks (16/CU) so the
// adj stream gets fill-kernel-class occupancy. Each thread: 2 (i,j) cells =
// 8 independent int4 loads + sk/sq float4s, ~130 VALU, coalesced f32 stores.
// No LDS, no shfl, no cross-lane deps.
// ---------------------------------------------------------------------------
__global__ __launch_bounds__(256) void k_scores(const int* __restrict__ adj,
                                                const float* __restrict__ sq,
                                                const float* __restrict__ sk,
                                                float* __restrict__ z) {
    int b = blockIdx.z;
    int i0 = blockIdx.y * 4;
    int j0 = blockIdx.x * 128;
    int t = threadIdx.x;
    int jj = t & 127, rg = (t >> 7) * 2;   // rows rg, rg+1
    int j = j0 + jj;
    const float4* kp = (const float4*)(sk + ((size_t)b * NN + j) * RR);
    float4 s0 = kp[0], s1 = kp[1], s2 = kp[2], s3 = kp[3];
    float ks[16] = {s0.x, s0.y, s0.z, s0.w, s1.x, s1.y, s1.z, s1.w,
                    s2.x, s2.y, s2.z, s2.w, s3.x, s3.y, s3.z, s3.w};
#pragma unroll
    for (int r = 0; r < 2; ++r) {
        int i = i0 + rg + r;
        const int4* ap = (const int4*)(adj + (((size_t)b * NN + i) * NN + j) * RR);
        int4 a0 = ap[0], a1 = ap[1], a2 = ap[2], a3 = ap[3];
        const float4* qp = (const float4*)(sq + ((size_t)b * NN + i) * RR);
        float4 q0 = qp[0], q1 = qp[1], q2 = qp[2], q3 = qp[3];
        float sv[16] = {q0.x, q0.y, q0.z, q0.w, q1.x, q1.y, q1.z, q1.w,
                        q2.x, q2.y, q2.z, q2.w, q3.x, q3.y, q3.z, q3.w};
        int av[16] = {a0.x, a0.y, a0.z, a0.w, a1.x, a1.y, a1.z, a1.w,
                      a2.x, a2.y, a2.z, a2.w, a3.x, a3.y, a3.z, a3.w};
        int any = 0;
        float ssum = 0.f;
#pragma unroll
        for (int ridx = 0; ridx < 16; ++ridx) {
            float v_ = sv[ridx] + ks[ridx];
            v_ = fmaxf(v_, 0.2f * v_);
            ssum = fmaf(v_, (float)av[ridx], ssum);
            any |= av[ridx];
        }
        z[((size_t)b * NN + i) * NN + j] = any ? ssum : -9e15f;
    }
}

// ---------------------------------------------------------------------------
// Softmax + PV: newx[b, m0..m0+16, :]. grid (32 i-tiles of 16, 8 b).
//   Phase B: z rows (32 KB, L3-hot) -> registers -> softmax -> P (bf16, LDS)
//   Phase C: newx = P(16x512) @ x via MFMA; B-frags 16-B loads from L2/L3-hot
//            xT_bf; epilogue scales by 1/rowsum.
// LDS: ~16.7 KB. All 16 P rows are real work.
// ---------------------------------------------------------------------------
__global__ __launch_bounds__(256) void k_attn_pv(const float* __restrict__ z,
                                                 const ushort* __restrict__ xT_bf,
                                                 ushort* __restrict__ newx_bf) {
    constexpr int ZS = 520;              // padded row stride (ushorts)
    __shared__ ushort P[16 * ZS];        // 16.6 KB
    __shared__ float  rowsum[16];
    int t = threadIdx.x;
    int b = blockIdx.y;
    int m0 = blockIdx.x * 16;

    // ---- Phase B: z -> registers -> softmax -> P ----
    {
        int r = t >> 4, cc = t & 15;    // r 0..15, cc 0..15
        const float* zr = z + ((size_t)b * NN + m0 + r) * NN;
        float zv[32];
#pragma unroll
        for (int it = 0; it < 32; ++it) zv[it] = zr[it * 16 + cc];
        float mx = zv[0];
#pragma unroll
        for (int it = 1; it < 32; ++it) mx = fmaxf(mx, zv[it]);
#pragma unroll
        for (int off = 1; off < 16; off <<= 1) mx = fmaxf(mx, __shfl_xor(mx, off, 64));
        float sum = 0.f;
        ushort* pr = &P[r * ZS];
#pragma unroll
        for (int it = 0; it < 32; ++it) {
            float e = __expf(zv[it] - mx);
            pr[it * 16 + cc] = bf16_bits(e);
            sum += e;
        }
#pragma unroll
        for (int off = 1; off < 16; off <<= 1) sum += __shfl_xor(sum, off, 64);
        if (cc == 0) rowsum[r] = sum;
    }
    __syncthreads();

    // ---- Phase C: newx tile = P(16x512) @ x(512x512) via MFMA ----
    {
        int w = t >> 6, lane = t & 63;
        int m_l = lane & 15, q = lane >> 4;
        int n0w = w * 128;
        f32x4 acc[8] = {};
        const ushort* xTb = xT_bf + (size_t)b * FF * NN;
        for (int k0 = 0; k0 < NN; k0 += 32) {
            short8 af = *(const short8*)(&P[m_l * ZS + k0 + q * 8]);
#pragma unroll
            for (int nb = 0; nb < 8; ++nb) {
                int n = n0w + nb * 16 + m_l;
                short8 bfr = *(const short8*)(xTb + (size_t)n * NN + k0 + q * 8);
                acc[nb] = __builtin_amdgcn_mfma_f32_16x16x32_bf16(af, bfr, acc[nb], 0, 0, 0);
            }
        }
        float inv[4];
#pragma unroll
        for (int rg = 0; rg < 4; ++rg) inv[rg] = 1.f / rowsum[q * 4 + rg];
#pragma unroll
        for (int nb = 0; nb < 8; ++nb) {
#pragma unroll
            for (int rg = 0; rg < 4; ++rg) {
                int i = m0 + q * 4 + rg;
                int f = n0w + nb * 16 + m_l;
                newx_bf[((size_t)b * NN + i) * FF + f] = bf16_bits(acc[nb][rg] * inv[rg]);
            }
        }
    }
}

// ---------------------------------------------------------------------------
// bf16 MFMA GEMM: C[b] (MxN) = A[b] (MxK row-major, split at k=512) @ BT^T
// 64x64 tile; two BK=32 stages per barrier-pair. grid (N/64, M/64, 8)
// ---------------------------------------------------------------------------
__global__ __launch_bounds__(256) void k_gemm(const ushort* __restrict__ A1, size_t sA1,
                                              const ushort* __restrict__ A2, size_t sA2,
                                              const ushort* __restrict__ BT, size_t sBT,
                                              float* __restrict__ Cf, size_t sC,
                                              int K, int ldBT) {
    __shared__ ushort As[2][64 * 40];  // stride 40 ushort = 80 B (16B-aligned rows)
    __shared__ ushort Bs[2][64 * 40];
    int t = threadIdx.x;
    int n0 = blockIdx.x * 64, m0 = blockIdx.y * 64, b = blockIdx.z;
    int row = t >> 2, c8 = (t & 3) * 8;
    int lane = t & 63, w = t >> 6;
    int m_l = lane & 15, q = lane >> 4;
    f32x4 acc[4] = {{0.f,0.f,0.f,0.f},{0.f,0.f,0.f,0.f},{0.f,0.f,0.f,0.f},{0.f,0.f,0.f,0.f}};
    const ushort* BTb = BT + (size_t)b * sBT;
    for (int k0 = 0; k0 < K; k0 += 64) {
#pragma unroll
        for (int h = 0; h < 2; ++h) {
            int kk = k0 + h * 32;
            const ushort* Aab; int kc;
            if (kk < FF) { Aab = A1 + (size_t)b * sA1; kc = kk; }
            else         { Aab = A2 + (size_t)b * sA2; kc = kk - FF; }
            uint4 av = *(const uint4*)(Aab + (size_t)(m0 + row) * FF + kc + c8);
            uint4 bv = *(const uint4*)(BTb + (size_t)(n0 + row) * ldBT + kk + c8);
            *(uint4*)(&As[h][row * 40 + c8]) = av;
            *(uint4*)(&Bs[h][row * 40 + c8]) = bv;
        }
        __syncthreads();
#pragma unroll
        for (int h = 0; h < 2; ++h) {
            short8 af = *(const short8*)(&As[h][(w * 16 + m_l) * 40 + q * 8]);
#pragma unroll
            for (int nb = 0; nb < 4; ++nb) {
                short8 bfr = *(const short8*)(&Bs[h][(nb * 16 + m_l) * 40 + q * 8]);
                acc[nb] = __builtin_amdgcn_mfma_f32_16x16x32_bf16(af, bfr, acc[nb], 0, 0, 0);
            }
        }
        __syncthreads();
    }
#pragma unroll
    for (int nb = 0; nb < 4; ++nb) {
#pragma unroll
        for (int r = 0; r < 4; ++r) {
            int mi = m0 + w * 16 + q * 4 + r;
            int ni = n0 + nb * 16 + m_l;
            Cf[(size_t)b * sC + (size_t)mi * FF + ni] = acc[nb][r];
        }
    }
}

// ---------------------------------------------------------------------------
// Launch
// ---------------------------------------------------------------------------
extern "C" void kernel_launch(void* const* d_in, const int* in_sizes, int n_in,
                              void* d_out, int out_size, void* d_ws, size_t ws_size,
                              hipStream_t stream) {
    const float* x_ori = (const float*)d_in[0];
    const float* x     = (const float*)d_in[1];
    const float* c     = (const float*)d_in[2];
    const int*   adj   = (const int*)d_in[3];
    const float* Wfc   = (const float*)d_in[4];
    const float* Wdc   = (const float*)d_in[5];
    const float* Wqv   = (const float*)d_in[6];
    const float* Wkv   = (const float*)d_in[7];
    const float* Wqc   = (const float*)d_in[8];
    const float* Wkc   = (const float*)d_in[9];
    const float* Wa    = (const float*)d_in[10];
    const float* Wu    = (const float*)d_in[11];
    float* out = (float*)d_out;

    char* ws = (char*)d_ws;
    float*  tb      = (float*)(ws + OFF_TB);
    float*  mb      = (float*)(ws + OFF_MB);
    float*  mq      = (float*)(ws + OFF_MQ);
    float*  mk      = (float*)(ws + OFF_MK);
    float*  sq      = (float*)(ws + OFF_SQ);
    float*  sk      = (float*)(ws + OFF_SK);
    ushort* WqEt    = (ushort*)(ws + OFF_WQET);
    ushort* WkEt    = (ushort*)(ws + OFF_WKET);
    ushort* x_bf    = (ushort*)(ws + OFF_XBF);
    ushort* xT_bf   = (ushort*)(ws + OFF_XTBF);
    ushort* xori_bf = (ushort*)(ws + OFF_XORIBF);
    ushort* newx_bf = (ushort*)(ws + OFF_NEWXBF);
    ushort* WuT     = (ushort*)(ws + OFF_WUT);
    float*  zbuf    = (float*)(ws + OFF_Z);

    dim3 blk(256);

    // 1) conversions/transposes + m-chain stage 1
    k_prep<<<dim3(3712), blk, 0, stream>>>(x_ori, x, c, Wfc, Wu,
                                           xori_bf, x_bf, xT_bf, WuT, tb);

    // 2) m-chain stages 2-3
    k_matvec<<<dim3(16, BSZ), blk, 0, stream>>>(tb, Wdc, mb);
    k_mqk<<<dim3(16, BSZ), blk, 0, stream>>>(mb, Wqc, Wkc, mq, mk);

    // 3) effective low-rank weights (q and k via blockIdx.z)
    k_weff<<<dim3(16, BSZ, 2), blk, 0, stream>>>(Wqv, Wkv, Wa, mq, mk, WqEt, WkEt);

    // 4) sq / sk via LDS-free MFMA
    k_sqsk<<<dim3(16, BSZ), blk, 0, stream>>>(x_bf, xori_bf, WqEt, WkEt, sq, sk);

    // 5a) masked scores, streaming at 16 blocks/CU (adj roofline term)
    k_scores<<<dim3(4, 128, BSZ), blk, 0, stream>>>(adj, sq, sk, zbuf);

    // 5b) softmax + PV -> newx (bf16)
    k_attn_pv<<<dim3(32, BSZ), blk, 0, stream>>>(zbuf, xT_bf, newx_bf);

    // 6) out = [x | new_x] @ Wu
    k_gemm<<<dim3(8, 8, BSZ), blk, 0, stream>>>(
        x_bf, (size_t)NN * FF, newx_bf, (size_t)NN * FF,
        WuT, (size_t)0, out, (size_t)NN * FF, TWOF, TWOF);
}

// Round 6
// 304.435 us; speedup vs baseline: 1.1901x; 1.0140x over previous
//
#include <hip/hip_runtime.h>
#include <hip/hip_bf16.h>
#include <cstddef>
#include <cstdint>

static constexpr int BSZ  = 8;
static constexpr int NN   = 512;
static constexpr int FF   = 512;
static constexpr int RR   = 16;
static constexpr int TWOF = 1024;

typedef __attribute__((ext_vector_type(8))) short short8;   // 8 bf16 in 4 VGPRs
typedef __attribute__((ext_vector_type(4))) float f32x4;

__device__ __forceinline__ ushort bf16_bits(float v) {
    union { __hip_bfloat16 h; ushort u; } cvt;
    cvt.h = __float2bfloat16(v);
    return cvt.u;
}

// ---------------------------------------------------------------------------
// Workspace layout (byte offsets, 256B aligned)
// ---------------------------------------------------------------------------
static constexpr size_t OFF_TB     = 0;         // f32 [8][512]
static constexpr size_t OFF_MB     = 16384;     // f32 [8][512]
static constexpr size_t OFF_MQ     = 32768;     // f32 [8][512]
static constexpr size_t OFF_MK     = 49152;     // f32 [8][512]
static constexpr size_t OFF_SQ     = 65536;     // f32 [8][512][16]
static constexpr size_t OFF_SK     = 327680;    // f32 [8][512][16]
static constexpr size_t OFF_WQET   = 589824;    // bf16 [8][16][1024]
static constexpr size_t OFF_WKET   = 851968;    // bf16 [8][16][1024]
static constexpr size_t OFF_XBF    = 5308416;   // bf16 [8][512][512]
static constexpr size_t OFF_XTBF   = 9502720;   // bf16 [8][512][512]  (x^T per b)
static constexpr size_t OFF_XORIBF = 13697024;  // bf16 [8][512][512]
static constexpr size_t OFF_NEWXBF = 17891328;  // bf16 [8][512][512]
static constexpr size_t OFF_WUT    = 22085632;  // bf16 [512][1024]    (Wu^T)
static constexpr size_t OFF_Z      = 23134208;  // f32  [8][512][512]  (scores)

// ---------------------------------------------------------------------------
// Fused prep kernel (R0 form):
//   blocks [0,1024):     x_ori -> xori_bf
//   blocks [1024,3072):  x -> x_bf + xT_bf (32x32 transpose tiles)
//   blocks [3072,3584):  Wu -> WuT_bf
//   blocks [3584,3712):  m-chain stage1: tb = elu(c @ Wfc)
// ---------------------------------------------------------------------------
__global__ __launch_bounds__(256) void k_prep(
    const float* __restrict__ x_ori, const float* __restrict__ x,
    const float* __restrict__ c, const float* __restrict__ Wfc,
    const float* __restrict__ Wu,
    ushort* __restrict__ xori_bf, ushort* __restrict__ x_bf,
    ushort* __restrict__ xT_bf, ushort* __restrict__ WuT,
    float* __restrict__ tb)
{
    int blk = blockIdx.x;
    int t = threadIdx.x;
    if (blk < 1024) {
        int idx = blk * 256 + t;
        float4 a = ((const float4*)x_ori)[idx * 2];
        float4 b = ((const float4*)x_ori)[idx * 2 + 1];
        uint4 s;
        s.x = (uint)bf16_bits(a.x) | ((uint)bf16_bits(a.y) << 16);
        s.y = (uint)bf16_bits(a.z) | ((uint)bf16_bits(a.w) << 16);
        s.z = (uint)bf16_bits(b.x) | ((uint)bf16_bits(b.y) << 16);
        s.w = (uint)bf16_bits(b.z) | ((uint)bf16_bits(b.w) << 16);
        ((uint4*)xori_bf)[idx] = s;
    } else if (blk < 3072) {
        __shared__ float tile[32][33];
        int bb = blk - 1024;
        int f0 = (bb & 15) * 32, i0 = ((bb >> 4) & 15) * 32, b = bb >> 8;
        int c2 = (t & 15) * 2, r = t >> 4;   // r in 0..15, c2 even in 0..30
#pragma unroll
        for (int rr = 0; rr < 32; rr += 16) {
            int i = i0 + r + rr;
            const float* xp = &x[((size_t)b * NN + i) * FF + f0 + c2];
            float v0 = xp[0], v1 = xp[1];
            tile[r + rr][c2] = v0;
            tile[r + rr][c2 + 1] = v1;
            *(uint*)&x_bf[((size_t)b * NN + i) * FF + f0 + c2] =
                (uint)bf16_bits(v0) | ((uint)bf16_bits(v1) << 16);
        }
        __syncthreads();
#pragma unroll
        for (int ff = 0; ff < 32; ff += 16) {
            int f = f0 + r + ff;
            *(uint*)&xT_bf[((size_t)b * FF + f) * NN + i0 + c2] =
                (uint)bf16_bits(tile[c2][r + ff]) |
                ((uint)bf16_bits(tile[c2 + 1][r + ff]) << 16);
        }
    } else if (blk < 3584) {
        __shared__ float tile2[32][33];
        int bb = blk - 3072;
        int f0 = (bb & 31) * 32, o0 = (bb >> 5) * 32;
        int cc = t & 31, r0 = t >> 5;
#pragma unroll
        for (int rr = 0; rr < 32; rr += 8)
            tile2[r0 + rr][cc] = Wu[(size_t)(f0 + r0 + rr) * FF + o0 + cc];
        __syncthreads();
#pragma unroll
        for (int rr = 0; rr < 32; rr += 8)
            WuT[(size_t)(o0 + r0 + rr) * TWOF + f0 + cc] = bf16_bits(tile2[cc][r0 + rr]);
    } else {
        // m-chain stage 1: tb = elu(c @ Wfc), grid-equivalent (16,8)
        __shared__ float red1[8][32];
        int bb = blk - 3584;
        int b = bb >> 4, f0 = (bb & 15) * 32;
        int f = t & 31, kq = t >> 5;
        const float* vb = c + (size_t)b * FF;
        float acc = 0.f;
        int ks = kq * 64;
#pragma unroll 8
        for (int k = ks; k < ks + 64; ++k)
            acc = fmaf(vb[k], Wfc[(size_t)k * FF + f0 + f], acc);
        red1[kq][f] = acc;
        __syncthreads();
        if (kq == 0) {
            acc += red1[1][f] + red1[2][f] + red1[3][f] + red1[4][f] +
                   red1[5][f] + red1[6][f] + red1[7][f];
            tb[(size_t)b * FF + f0 + f] = (acc > 0.f) ? acc : expm1f(acc);
        }
    }
}

// ---------------------------------------------------------------------------
// Batched GEMV: vout[b,f] = vin[b,:] @ W[:,f]
// grid (16 fb, 8 b), block 256 = (32 f, 8 kq)
// ---------------------------------------------------------------------------
__global__ __launch_bounds__(256) void k_matvec(const float* __restrict__ vin,
                                                const float* __restrict__ W,
                                                float* __restrict__ vout) {
    __shared__ float red[8][32];
    int b = blockIdx.y;
    int f0 = blockIdx.x * 32;
    int t = threadIdx.x;
    int f = t & 31, kq = t >> 5;
    const float* vb = vin + (size_t)b * FF;
    float acc = 0.f;
    int ks = kq * 64;
#pragma unroll 8
    for (int k = ks; k < ks + 64; ++k)
        acc = fmaf(vb[k], W[(size_t)k * FF + f0 + f], acc);
    red[kq][f] = acc;
    __syncthreads();
    if (kq == 0) {
        acc += red[1][f] + red[2][f] + red[3][f] + red[4][f] +
               red[5][f] + red[6][f] + red[7][f];
        vout[(size_t)b * FF + f0 + f] = acc;
    }
}

// mq = m @ Wqc ; mk = m @ Wkc
__global__ __launch_bounds__(256) void k_mqk(const float* __restrict__ m,
                                             const float* __restrict__ Wqc,
                                             const float* __restrict__ Wkc,
                                             float* __restrict__ mq,
                                             float* __restrict__ mk) {
    __shared__ float redq[8][32];
    __shared__ float redk[8][32];
    int b = blockIdx.y;
    int f0 = blockIdx.x * 32;
    int t = threadIdx.x;
    int f = t & 31, kq = t >> 5;
    const float* mb = m + (size_t)b * FF;
    float aq = 0.f, ak = 0.f;
    int ks = kq * 64;
#pragma unroll 8
    for (int k = ks; k < ks + 64; ++k) {
        float mv = mb[k];
        aq = fmaf(mv, Wqc[(size_t)k * FF + f0 + f], aq);
        ak = fmaf(mv, Wkc[(size_t)k * FF + f0 + f], ak);
    }
    redq[kq][f] = aq;
    redk[kq][f] = ak;
    __syncthreads();
    if (kq == 0) {
        aq += redq[1][f] + redq[2][f] + redq[3][f] + redq[4][f] +
              redq[5][f] + redq[6][f] + redq[7][f];
        ak += redk[1][f] + redk[2][f] + redk[3][f] + redk[4][f] +
              redk[5][f] + redk[6][f] + redk[7][f];
        mq[(size_t)b * FF + f0 + f] = aq;
        mk[(size_t)b * FF + f0 + f] = ak;
    }
}

// ---------------------------------------------------------------------------
// W_eff^T[b,r,k] = sum_f W[k,f] * mvec[b,f] * Wa[waRowOff+f, r]  (bf16 out)
// grid (16 kchunks, 8 b, 2 {q,k}), block 256.  f-loop vectorized x4.
// ---------------------------------------------------------------------------
__global__ __launch_bounds__(256) void k_weff(const float* __restrict__ Wqv,
                                              const float* __restrict__ Wkv,
                                              const float* __restrict__ Wa,
                                              const float* __restrict__ mqv,
                                              const float* __restrict__ mkv,
                                              ushort* __restrict__ WqEt,
                                              ushort* __restrict__ WkEt) {
    int z = blockIdx.z;
    const float* W = z ? Wkv : Wqv;
    const float* mvec = z ? mkv : mqv;
    ushort* WeffT = z ? WkEt : WqEt;
    int waRowOff = z ? FF : 0;

    __shared__ float4 wa4[FF * 4];  // [f][r4] scaled Wa, 32 KiB
    int tid = threadIdx.x;
    int b = blockIdx.y;
    const float* mv = mvec + (size_t)b * FF;
#pragma unroll
    for (int qq = 0; qq < 8; ++qq) {
        int idx = tid + qq * 256;
        int f = idx >> 2, rq = idx & 3;
        float4 w = *reinterpret_cast<const float4*>(Wa + (size_t)(waRowOff + f) * RR + rq * 4);
        float s = mv[f];
        float4 o;
        o.x = w.x * s; o.y = w.y * s; o.z = w.z * s; o.w = w.w * s;
        wa4[idx] = o;
    }
    __syncthreads();
    int k_l = tid >> 2, r4 = tid & 3;
    int k = blockIdx.x * 64 + k_l;
    const float4* Wrow4 = reinterpret_cast<const float4*>(W + (size_t)k * FF);
    float4 acc = {0.f, 0.f, 0.f, 0.f};
#pragma unroll 4
    for (int f4 = 0; f4 < FF / 4; ++f4) {
        float4 w = Wrow4[f4];
        float4 v0 = wa4[(f4 * 4 + 0) * 4 + r4];
        float4 v1 = wa4[(f4 * 4 + 1) * 4 + r4];
        float4 v2 = wa4[(f4 * 4 + 2) * 4 + r4];
        float4 v3 = wa4[(f4 * 4 + 3) * 4 + r4];
        acc.x = fmaf(w.x, v0.x, acc.x); acc.y = fmaf(w.x, v0.y, acc.y);
        acc.z = fmaf(w.x, v0.z, acc.z); acc.w = fmaf(w.x, v0.w, acc.w);
        acc.x = fmaf(w.y, v1.x, acc.x); acc.y = fmaf(w.y, v1.y, acc.y);
        acc.z = fmaf(w.y, v1.z, acc.z); acc.w = fmaf(w.y, v1.w, acc.w);
        acc.x = fmaf(w.z, v2.x, acc.x); acc.y = fmaf(w.z, v2.y, acc.y);
        acc.z = fmaf(w.z, v2.z, acc.z); acc.w = fmaf(w.z, v2.w, acc.w);
        acc.x = fmaf(w.w, v3.x, acc.x); acc.y = fmaf(w.w, v3.y, acc.y);
        acc.z = fmaf(w.w, v3.z, acc.z); acc.w = fmaf(w.w, v3.w, acc.w);
    }
    WeffT[((size_t)b * RR + r4 * 4 + 0) * TWOF + k] = bf16_bits(acc.x);
    WeffT[((size_t)b * RR + r4 * 4 + 1) * TWOF + k] = bf16_bits(acc.y);
    WeffT[((size_t)b * RR + r4 * 4 + 2) * TWOF + k] = bf16_bits(acc.z);
    WeffT[((size_t)b * RR + r4 * 4 + 3) * TWOF + k] = bf16_bits(acc.w);
}

// ---------------------------------------------------------------------------
// sq/sk via MFMA, LDS-free. grid (16 m-tiles of 32, 8 b), block 256 = 4 waves
// ---------------------------------------------------------------------------
__global__ __launch_bounds__(256) void k_sqsk(const ushort* __restrict__ x_bf,
                                              const ushort* __restrict__ xori_bf,
                                              const ushort* __restrict__ WqEt,
                                              const ushort* __restrict__ WkEt,
                                              float* __restrict__ sq,
                                              float* __restrict__ sk) {
    int t = threadIdx.x;
    int b = blockIdx.y;
    int m0 = blockIdx.x * 32;
    int lane = t & 63, w = t >> 6;
    int sub = w & 1, isK = w >> 1;
    int m_l = lane & 15, q = lane >> 4;
    int row = m0 + sub * 16 + m_l;
    const ushort* Bt = (isK ? WkEt : WqEt) + ((size_t)b * RR + m_l) * TWOF;
    f32x4 acc = {0.f, 0.f, 0.f, 0.f};
#pragma unroll
    for (int k0 = 0; k0 < TWOF; k0 += 32) {
        const ushort* src = (k0 < FF) ? x_bf : xori_bf;
        int kc = k0 & (FF - 1);
        short8 af = *(const short8*)(src + ((size_t)b * NN + row) * FF + kc + q * 8);
        short8 bf = *(const short8*)(Bt + k0 + q * 8);
        acc = __builtin_amdgcn_mfma_f32_16x16x32_bf16(af, bf, acc, 0, 0, 0);
    }
    float* dst = isK ? sk : sq;
#pragma unroll
    for (int r = 0; r < 4; ++r) {
        int i = m0 + sub * 16 + q * 4 + r;
        dst[((size_t)b * NN + i) * RR + m_l] = acc[r];
    }
}

// ---------------------------------------------------------------------------
// Masked scores, streaming kernel v2 (the adj roofline term).
// z[b,i,j] = sum_r leakyrelu(sq[b,i,r]+sk[b,j,r]) * adj[b,i,j,r], or -9e15.
// grid (2 j-halves, 512 i, 8 b) = 8192 blocks (~8/CU, up to 32 waves/CU):
//   - ONE cell per thread; each block reads a CONTIGUOUS 16 KB adj span and
//     consecutive block ids sweep adj sequentially.
//   - i is per-block => sq row is wave-uniform => SGPR loads (no VGPR/lane
//     traffic). Explicit int4/float4 vars keep VGPR low for 8 waves/SIMD.
// ---------------------------------------------------------------------------
__global__ __launch_bounds__(256) void k_scores(const int* __restrict__ adj,
                                                const float* __restrict__ sq,
                                                const float* __restrict__ sk,
                                                float* __restrict__ z) {
    int b = blockIdx.z;
    int i = blockIdx.y;
    int j = blockIdx.x * 256 + threadIdx.x;

    const float4* qp = (const float4*)(sq + ((size_t)b * NN + i) * RR);  // uniform
    float4 q0 = qp[0], q1 = qp[1], q2 = qp[2], q3 = qp[3];

    const int4* ap = (const int4*)(adj + (((size_t)b * NN + i) * NN + j) * RR);
    int4 a0 = ap[0], a1 = ap[1], a2 = ap[2], a3 = ap[3];

    const float4* kp = (const float4*)(sk + ((size_t)b * NN + j) * RR);
    float4 s0 = kp[0], s1 = kp[1], s2 = kp[2], s3 = kp[3];

    float ssum = 0.f;
    int any = 0;
#define LR_TERM(QV, SV, AV)                               \
    { float v_ = (QV) + (SV);                             \
      v_ = fmaxf(v_, 0.2f * v_);                          \
      ssum = fmaf(v_, (float)(AV), ssum); any |= (AV); }
    LR_TERM(q0.x, s0.x, a0.x)  LR_TERM(q0.y, s0.y, a0.y)
    LR_TERM(q0.z, s0.z, a0.z)  LR_TERM(q0.w, s0.w, a0.w)
    LR_TERM(q1.x, s1.x, a1.x)  LR_TERM(q1.y, s1.y, a1.y)
    LR_TERM(q1.z, s1.z, a1.z)  LR_TERM(q1.w, s1.w, a1.w)
    LR_TERM(q2.x, s2.x, a2.x)  LR_TERM(q2.y, s2.y, a2.y)
    LR_TERM(q2.z, s2.z, a2.z)  LR_TERM(q2.w, s2.w, a2.w)
    LR_TERM(q3.x, s3.x, a3.x)  LR_TERM(q3.y, s3.y, a3.y)
    LR_TERM(q3.z, s3.z, a3.z)  LR_TERM(q3.w, s3.w, a3.w)
#undef LR_TERM
    z[((size_t)b * NN + i) * NN + j] = any ? ssum : -9e15f;
}

// ---------------------------------------------------------------------------
// Softmax + PV: newx[b, m0..m0+16, f-half]. grid (64, 8) = 512 blocks (2/CU):
//   blockIdx.x = (i-tile << 1) | f-half. Phase B (softmax) is duplicated per
//   half (cheap); phase C's xT reads are NOT duplicated (each half reads its
//   own 256 xT rows). 2 blocks/CU lets one block's z/xT loads overlap the
//   sibling's MFMA.
//   Phase B: z rows via float4 loads -> registers -> softmax -> P (uint2 LDS)
//   Phase C: newx(16 x 256-half) = P @ x via MFMA; epilogue scales by 1/rowsum.
// LDS: ~16.7 KB.
// ---------------------------------------------------------------------------
__global__ __launch_bounds__(256) void k_attn_pv(const float* __restrict__ z,
                                                 const ushort* __restrict__ xT_bf,
                                                 ushort* __restrict__ newx_bf) {
    constexpr int ZS = 520;              // padded row stride (ushorts)
    __shared__ ushort P[16 * ZS];        // 16.6 KB
    __shared__ float  rowsum[16];
    int t = threadIdx.x;
    int b = blockIdx.y;
    int half = blockIdx.x & 1;
    int m0 = (blockIdx.x >> 1) * 16;

    // ---- Phase B: z -> registers (float4) -> softmax -> P ----
    {
        int r = t >> 4, cc = t & 15;    // r 0..15, cc 0..15
        const float4* zr = (const float4*)(z + ((size_t)b * NN + m0 + r) * NN) + cc;
        float4 zf[8];
#pragma unroll
        for (int it = 0; it < 8; ++it) zf[it] = zr[it * 16];
        float mx = -3.0e38f;
#pragma unroll
        for (int it = 0; it < 8; ++it) {
            mx = fmaxf(mx, fmaxf(fmaxf(zf[it].x, zf[it].y), fmaxf(zf[it].z, zf[it].w)));
        }
#pragma unroll
        for (int off = 1; off < 16; off <<= 1) mx = fmaxf(mx, __shfl_xor(mx, off, 64));
        float sum = 0.f;
        ushort* pr = &P[r * ZS];
#pragma unroll
        for (int it = 0; it < 8; ++it) {
            float e0 = __expf(zf[it].x - mx);
            float e1 = __expf(zf[it].y - mx);
            float e2 = __expf(zf[it].z - mx);
            float e3 = __expf(zf[it].w - mx);
            uint lo = (uint)bf16_bits(e0) | ((uint)bf16_bits(e1) << 16);
            uint hi = (uint)bf16_bits(e2) | ((uint)bf16_bits(e3) << 16);
            uint2 pk; pk.x = lo; pk.y = hi;
            *(uint2*)&pr[it * 64 + cc * 4] = pk;
            sum += e0 + e1 + e2 + e3;
        }
#pragma unroll
        for (int off = 1; off < 16; off <<= 1) sum += __shfl_xor(sum, off, 64);
        if (cc == 0) rowsum[r] = sum;
    }
    __syncthreads();

    // ---- Phase C: newx half-tile = P(16x512) @ x-half via MFMA ----
    {
        int w = t >> 6, lane = t & 63;
        int m_l = lane & 15, q = lane >> 4;
        int n0w = half * 256 + w * 64;
        f32x4 acc[4] = {};
        const ushort* xTb = xT_bf + (size_t)b * FF * NN;
        for (int k0 = 0; k0 < NN; k0 += 32) {
            short8 af = *(const short8*)(&P[m_l * ZS + k0 + q * 8]);
#pragma unroll
            for (int nb = 0; nb < 4; ++nb) {
                int n = n0w + nb * 16 + m_l;
                short8 bfr = *(const short8*)(xTb + (size_t)n * NN + k0 + q * 8);
                acc[nb] = __builtin_amdgcn_mfma_f32_16x16x32_bf16(af, bfr, acc[nb], 0, 0, 0);
            }
        }
        float inv[4];
#pragma unroll
        for (int rg = 0; rg < 4; ++rg) inv[rg] = 1.f / rowsum[q * 4 + rg];
#pragma unroll
        for (int nb = 0; nb < 4; ++nb) {
#pragma unroll
            for (int rg = 0; rg < 4; ++rg) {
                int i = m0 + q * 4 + rg;
                int f = n0w + nb * 16 + m_l;
                newx_bf[((size_t)b * NN + i) * FF + f] = bf16_bits(acc[nb][rg] * inv[rg]);
            }
        }
    }
}

// ---------------------------------------------------------------------------
// bf16 MFMA GEMM: C[b] (MxN) = A[b] (MxK row-major, split at k=512) @ BT^T
// 64x64 tile; two BK=32 stages per barrier-pair. grid (N/64, M/64, 8)
// ---------------------------------------------------------------------------
__global__ __launch_bounds__(256) void k_gemm(const ushort* __restrict__ A1, size_t sA1,
                                              const ushort* __restrict__ A2, size_t sA2,
                                              const ushort* __restrict__ BT, size_t sBT,
                                              float* __restrict__ Cf, size_t sC,
                                              int K, int ldBT) {
    __shared__ ushort As[2][64 * 40];  // stride 40 ushort = 80 B (16B-aligned rows)
    __shared__ ushort Bs[2][64 * 40];
    int t = threadIdx.x;
    int n0 = blockIdx.x * 64, m0 = blockIdx.y * 64, b = blockIdx.z;
    int row = t >> 2, c8 = (t & 3) * 8;
    int lane = t & 63, w = t >> 6;
    int m_l = lane & 15, q = lane >> 4;
    f32x4 acc[4] = {{0.f,0.f,0.f,0.f},{0.f,0.f,0.f,0.f},{0.f,0.f,0.f,0.f},{0.f,0.f,0.f,0.f}};
    const ushort* BTb = BT + (size_t)b * sBT;
    for (int k0 = 0; k0 < K; k0 += 64) {
#pragma unroll
        for (int h = 0; h < 2; ++h) {
            int kk = k0 + h * 32;
            const ushort* Aab; int kc;
            if (kk < FF) { Aab = A1 + (size_t)b * sA1; kc = kk; }
            else         { Aab = A2 + (size_t)b * sA2; kc = kk - FF; }
            uint4 av = *(const uint4*)(Aab + (size_t)(m0 + row) * FF + kc + c8);
            uint4 bv = *(const uint4*)(BTb + (size_t)(n0 + row) * ldBT + kk + c8);
            *(uint4*)(&As[h][row * 40 + c8]) = av;
            *(uint4*)(&Bs[h][row * 40 + c8]) = bv;
        }
        __syncthreads();
#pragma unroll
        for (int h = 0; h < 2; ++h) {
            short8 af = *(const short8*)(&As[h][(w * 16 + m_l) * 40 + q * 8]);
#pragma unroll
            for (int nb = 0; nb < 4; ++nb) {
                short8 bfr = *(const short8*)(&Bs[h][(nb * 16 + m_l) * 40 + q * 8]);
                acc[nb] = __builtin_amdgcn_mfma_f32_16x16x32_bf16(af, bfr, acc[nb], 0, 0, 0);
            }
        }
        __syncthreads();
    }
#pragma unroll
    for (int nb = 0; nb < 4; ++nb) {
#pragma unroll
        for (int r = 0; r < 4; ++r) {
            int mi = m0 + w * 16 + q * 4 + r;
            int ni = n0 + nb * 16 + m_l;
            Cf[(size_t)b * sC + (size_t)mi * FF + ni] = acc[nb][r];
        }
    }
}

// ---------------------------------------------------------------------------
// Launch
// ---------------------------------------------------------------------------
extern "C" void kernel_launch(void* const* d_in, const int* in_sizes, int n_in,
                              void* d_out, int out_size, void* d_ws, size_t ws_size,
                              hipStream_t stream) {
    const float* x_ori = (const float*)d_in[0];
    const float* x     = (const float*)d_in[1];
    const float* c     = (const float*)d_in[2];
    const int*   adj   = (const int*)d_in[3];
    const float* Wfc   = (const float*)d_in[4];
    const float* Wdc   = (const float*)d_in[5];
    const float* Wqv   = (const float*)d_in[6];
    const float* Wkv   = (const float*)d_in[7];
    const float* Wqc   = (const float*)d_in[8];
    const float* Wkc   = (const float*)d_in[9];
    const float* Wa    = (const float*)d_in[10];
    const float* Wu    = (const float*)d_in[11];
    float* out = (float*)d_out;

    char* ws = (char*)d_ws;
    float*  tb      = (float*)(ws + OFF_TB);
    float*  mb      = (float*)(ws + OFF_MB);
    float*  mq      = (float*)(ws + OFF_MQ);
    float*  mk      = (float*)(ws + OFF_MK);
    float*  sq      = (float*)(ws + OFF_SQ);
    float*  sk      = (float*)(ws + OFF_SK);
    ushort* WqEt    = (ushort*)(ws + OFF_WQET);
    ushort* WkEt    = (ushort*)(ws + OFF_WKET);
    ushort* x_bf    = (ushort*)(ws + OFF_XBF);
    ushort* xT_bf   = (ushort*)(ws + OFF_XTBF);
    ushort* xori_bf = (ushort*)(ws + OFF_XORIBF);
    ushort* newx_bf = (ushort*)(ws + OFF_NEWXBF);
    ushort* WuT     = (ushort*)(ws + OFF_WUT);
    float*  zbuf    = (float*)(ws + OFF_Z);

    dim3 blk(256);

    // 1) conversions/transposes + m-chain stage 1
    k_prep<<<dim3(3712), blk, 0, stream>>>(x_ori, x, c, Wfc, Wu,
                                           xori_bf, x_bf, xT_bf, WuT, tb);

    // 2) m-chain stages 2-3
    k_matvec<<<dim3(16, BSZ), blk, 0, stream>>>(tb, Wdc, mb);
    k_mqk<<<dim3(16, BSZ), blk, 0, stream>>>(mb, Wqc, Wkc, mq, mk);

    // 3) effective low-rank weights (q and k via blockIdx.z)
    k_weff<<<dim3(16, BSZ, 2), blk, 0, stream>>>(Wqv, Wkv, Wa, mq, mk, WqEt, WkEt);

    // 4) sq / sk via LDS-free MFMA
    k_sqsk<<<dim3(16, BSZ), blk, 0, stream>>>(x_bf, xori_bf, WqEt, WkEt, sq, sk);

    // 5a) masked scores: 1 cell/thread, sequential adj sweep, ~8 blocks/CU
    k_scores<<<dim3(2, 512, BSZ), blk, 0, stream>>>(adj, sq, sk, zbuf);

    // 5b) softmax + PV -> newx (bf16), f-split for 2 blocks/CU
    k_attn_pv<<<dim3(64, BSZ), blk, 0, stream>>>(zbuf, xT_bf, newx_bf);

    // 6) out = [x | new_x] @ Wu
    k_gemm<<<dim3(8, 8, BSZ), blk, 0, stream>>>(
        x_bf, (size_t)NN * FF, newx_bf, (size_t)NN * FF,
        WuT, (size_t)0, out, (size_t)NN * FF, TWOF, TWOF);
}